// Round 3
// baseline (1388.373 us; speedup 1.0000x reference)
//
#include <hip/hip_runtime.h>
#include <stdint.h>

typedef unsigned short u16;
typedef unsigned int   u32;

#define B_  128
#define S_  512
#define D_  256
#define L_  3
#define H_  8
#define AD_ 64
#define HD_ 32
#define N_  (B_*S_)

typedef __bf16 bf16x8 __attribute__((ext_vector_type(8)));
typedef float  f32x4  __attribute__((ext_vector_type(4)));

__device__ __forceinline__ float bf2f(u16 u){ return __uint_as_float(((u32)u)<<16); }
__device__ __forceinline__ u16 f2bf(float f){
  u32 u = __float_as_uint(f);
  u32 r = u + 0x7fffu + ((u>>16)&1u);
  return (u16)(r>>16);
}
__device__ __forceinline__ u32 pack2(float lo, float hi){
  return (u32)f2bf(lo) | ((u32)f2bf(hi)<<16);
}

// ---------------------------------------------------------------------------
// K0a: dtype detection. bf16 tensors from N(0,1) never have exponent >= 0x90
// (|x| >= 2^17); fp32 bits read as u16 pairs have ~uniform low halves (~22%
// of all u16s have "exp" >= 0x90). Count over 4096 u16s: 0 vs ~900.
// Round-2 evidence: flag==1 (inputs fp32) — matches reference jnp.float32.
// ---------------------------------------------------------------------------
__launch_bounds__(64)
__global__ void detect_kernel(const u16* __restrict__ f0, int* __restrict__ flag){
  int lane = threadIdx.x;
  int cnt = 0;
  for (int i = lane; i < 4096; i += 64){
    u16 v = f0[i];
    int e = (v >> 7) & 0xff;
    cnt += (e >= 0x90);
  }
  #pragma unroll
  for (int o=32;o>0;o>>=1) cnt += __shfl_xor(cnt, o, 64);
  if (lane==0) *flag = (cnt > 128) ? 1 : 0;   // 1 => fp32
}

// ---------------------------------------------------------------------------
// K0b: canonicalize the 18 small float arrays (weights/biases/LN params) to
// bf16 in ws, honoring the detected input dtype.
// ---------------------------------------------------------------------------
struct CvtArgs {
  const void* src[18];
  int cum[19];
};

__launch_bounds__(256)
__global__ void convert_kernel(CvtArgs a, const int* __restrict__ flag, u16* __restrict__ dst){
  int isf32 = *flag;
  int total = a.cum[18];
  for (int g = blockIdx.x*blockDim.x + threadIdx.x; g < total; g += gridDim.x*blockDim.x){
    int arr = 0;
    while (g >= a.cum[arr+1]) arr++;
    int idx = g - a.cum[arr];
    float v = isf32 ? ((const float*)a.src[arr])[idx]
                    : bf2f(((const u16*)a.src[arr])[idx]);
    dst[g] = f2bf(v);
  }
}

// ---------------------------------------------------------------------------
// K1: per-(graph, scale) mean pooling over 512 rows -> G_mean [B,L,D] fp32
// ---------------------------------------------------------------------------
__launch_bounds__(256)
__global__ void mean_pool_kernel(const void* __restrict__ f0, const void* __restrict__ f1,
                                 const void* __restrict__ f2, const int* __restrict__ flag,
                                 float* __restrict__ gmean){
  __shared__ float part[8][256];
  int bx = blockIdx.x;
  int l = bx % 3, b = bx / 3;
  const void* f = (l==0)?f0:((l==1)?f1:f2);
  int tid = threadIdx.x;
  int cg = (tid & 31) << 3;   // column group start (8 elements)
  int sg = tid >> 5;          // row group 0..7
  int isf32 = *flag;
  float acc[8];
  #pragma unroll
  for (int i=0;i<8;i++) acc[i]=0.f;
  if (isf32){
    const float* base = (const float*)f + (size_t)b*S_*D_;
    for (int s = sg; s < S_; s += 8){
      float4 p0 = *(const float4*)(base + (size_t)s*D_ + cg);
      float4 p1 = *(const float4*)(base + (size_t)s*D_ + cg + 4);
      acc[0]+=p0.x; acc[1]+=p0.y; acc[2]+=p0.z; acc[3]+=p0.w;
      acc[4]+=p1.x; acc[5]+=p1.y; acc[6]+=p1.z; acc[7]+=p1.w;
    }
  } else {
    const u16* base = (const u16*)f + (size_t)b*S_*D_;
    for (int s = sg; s < S_; s += 8){
      uint4 p = *(const uint4*)(base + (size_t)s*D_ + cg);
      u32 uu[4]={p.x,p.y,p.z,p.w};
      #pragma unroll
      for (int j=0;j<4;j++){
        acc[2*j]   += __uint_as_float(uu[j]<<16);
        acc[2*j+1] += __uint_as_float(uu[j]&0xffff0000u);
      }
    }
  }
  #pragma unroll
  for (int j=0;j<8;j++) part[sg][cg+j] = acc[j];
  __syncthreads();
  float s2 = 0.f;
  #pragma unroll
  for (int g=0; g<8; g++) s2 += part[g][tid];
  gmean[(size_t)(b*3+l)*256 + tid] = s2 * (1.0f/512.0f);
}

// ---------------------------------------------------------------------------
// K2: tiny per-graph scale attention -> scale_w [B,L] fp32.  1 wave / graph.
// ---------------------------------------------------------------------------
__launch_bounds__(64)
__global__ void scale_attn_kernel(const float* __restrict__ gmean,
                                  const u16* __restrict__ Wq_s, const u16* __restrict__ bq_s,
                                  const u16* __restrict__ Wk_s, const u16* __restrict__ bk_s,
                                  const u16* __restrict__ Wv_s, const u16* __restrict__ bv_s,
                                  float* __restrict__ scale_w){
  __shared__ float G[3][256];
  __shared__ float qs[3][64], ks[3][64], vs[3][64];
  __shared__ float A[3][3];
  __shared__ float sw[3];
  int a = threadIdx.x;
  int b = blockIdx.x;
  for (int i = a; i < 3*256; i += 64) ((float*)G)[i] = gmean[(size_t)b*768 + i];
  if (a < 3) sw[a] = 0.f;
  __syncthreads();
  for (int l=0;l<3;l++){
    float accq = bf2f(bq_s[a]), acck = bf2f(bk_s[a]), accv = bf2f(bv_s[a]);
    for (int d=0; d<256; d++){
      float g = G[l][d];
      accq += g * bf2f(Wq_s[a*256+d]);
      acck += g * bf2f(Wk_s[a*256+d]);
      accv += g * bf2f(Wv_s[a*256+d]);
    }
    qs[l][a]=accq; ks[l][a]=acck; vs[l][a]=accv;
  }
  __syncthreads();
  if (a < 9){
    int l=a/3, m=a%3;
    float s=0.f;
    for (int j=0;j<64;j++) s += qs[l][j]*ks[m][j];
    A[l][m] = s * 0.125f;   // / sqrt(AD=64)
  }
  __syncthreads();
  if (a < 3){
    float mx = fmaxf(A[a][0], fmaxf(A[a][1],A[a][2]));
    float e0=expf(A[a][0]-mx), e1=expf(A[a][1]-mx), e2=expf(A[a][2]-mx);
    float inv = 1.f/(e0+e1+e2);
    A[a][0]=e0*inv; A[a][1]=e1*inv; A[a][2]=e2*inv;
  }
  __syncthreads();
  float g0=0.f,g1=0.f,g2=0.f;
  for (int m=0;m<3;m++){
    float v = vs[m][a];
    g0 += A[0][m]*v; g1 += A[1][m]*v; g2 += A[2][m]*v;
  }
  float mx = fmaxf(g0,fmaxf(g1,g2));
  float e0=expf(g0-mx), e1=expf(g1-mx), e2=expf(g2-mx);
  float inv = 1.f/(e0+e1+e2);
  atomicAdd(&sw[0], e0*inv);
  atomicAdd(&sw[1], e1*inv);
  atomicAdd(&sw[2], e2*inv);
  __syncthreads();
  if (a < 3) scale_w[b*3+a] = sw[a] * (1.0f/64.0f);
}

// ---------------------------------------------------------------------------
// K3: fused[n,:] = sum_l w[batch[n],l] * feat_l[n,:]   (bf16 out)
// ---------------------------------------------------------------------------
__launch_bounds__(256)
__global__ void fuse_kernel(const void* __restrict__ f0, const void* __restrict__ f1,
                            const void* __restrict__ f2, const int* __restrict__ batch,
                            const int* __restrict__ flag,
                            const float* __restrict__ scale_w, u16* __restrict__ fused){
  int idx = blockIdx.x*256 + threadIdx.x;  // 8-elem chunk id
  int n  = idx >> 5;
  int c8 = (idx & 31) << 3;
  int b = batch[n];
  int isf32 = *flag;
  float w0 = scale_w[b*3+0], w1 = scale_w[b*3+1], w2 = scale_w[b*3+2];
  size_t off = (size_t)n*256 + c8;
  float e[8];
  if (isf32){
    const float* p0 = (const float*)f0 + off;
    const float* p1 = (const float*)f1 + off;
    const float* p2 = (const float*)f2 + off;
    float4 a0 = *(const float4*)(p0),   a1 = *(const float4*)(p0+4);
    float4 b0 = *(const float4*)(p1),   b1 = *(const float4*)(p1+4);
    float4 c0 = *(const float4*)(p2),   c1 = *(const float4*)(p2+4);
    e[0]=w0*a0.x+w1*b0.x+w2*c0.x; e[1]=w0*a0.y+w1*b0.y+w2*c0.y;
    e[2]=w0*a0.z+w1*b0.z+w2*c0.z; e[3]=w0*a0.w+w1*b0.w+w2*c0.w;
    e[4]=w0*a1.x+w1*b1.x+w2*c1.x; e[5]=w0*a1.y+w1*b1.y+w2*c1.y;
    e[6]=w0*a1.z+w1*b1.z+w2*c1.z; e[7]=w0*a1.w+w1*b1.w+w2*c1.w;
  } else {
    uint4 p0 = *(const uint4*)((const u16*)f0+off);
    uint4 p1 = *(const uint4*)((const u16*)f1+off);
    uint4 p2 = *(const uint4*)((const u16*)f2+off);
    u32 a0[4]={p0.x,p0.y,p0.z,p0.w}, a1[4]={p1.x,p1.y,p1.z,p1.w}, a2[4]={p2.x,p2.y,p2.z,p2.w};
    #pragma unroll
    for (int j=0;j<4;j++){
      e[2*j]   = w0*__uint_as_float(a0[j]<<16) + w1*__uint_as_float(a1[j]<<16)
               + w2*__uint_as_float(a2[j]<<16);
      e[2*j+1] = w0*__uint_as_float(a0[j]&0xffff0000u) + w1*__uint_as_float(a1[j]&0xffff0000u)
               + w2*__uint_as_float(a2[j]&0xffff0000u);
    }
  }
  uint4 o;
  o.x = pack2(e[0],e[1]); o.y = pack2(e[2],e[3]);
  o.z = pack2(e[4],e[5]); o.w = pack2(e[6],e[7]);
  *(uint4*)(fused+off) = o;
}

// ---------------------------------------------------------------------------
// K4: NT GEMM  C[M,N] = X[M,K] @ W[N,K]^T + bias, bf16 in/out, fp32 acc.
// 64x64 block tile, 4 waves, MFMA 16x16x32 bf16.
// Layouts (HW-verified): A-frag m=lane&15, k=quad*8+j ; B-frag n=lane&15,
// k=quad*8+j ; D col=lane&15, row=quad*4+reg.
// ---------------------------------------------------------------------------
__launch_bounds__(256)
__global__ void gemm_nt_kernel(const u16* __restrict__ Xg, const u16* __restrict__ Wg,
                               const u16* __restrict__ bias, u16* __restrict__ Cg,
                               int M, int Nn, int Kd){
  __shared__ __align__(16) __bf16 As[64][40];   // +8 pad, rows stay 16B aligned
  __shared__ __align__(16) __bf16 Bs[64][40];
  int tid = threadIdx.x;
  int w = tid >> 6, l = tid & 63;
  int m0 = blockIdx.y*64, n0 = blockIdx.x*64;
  int lrow = tid >> 2;            // staging row 0..63
  int lcg  = (tid & 3) << 3;      // staging col group 0,8,16,24
  int frow = l & 15, quad = l >> 4;

  f32x4 acc[4];
  #pragma unroll
  for (int t=0;t<4;t++){
    #pragma unroll
    for (int i=0;i<4;i++) acc[t][i] = 0.f;
  }

  for (int k0 = 0; k0 < Kd; k0 += 32){
    __syncthreads();
    *(uint4*)&As[lrow][lcg] = *(const uint4*)(Xg + (size_t)(m0+lrow)*Kd + k0 + lcg);
    *(uint4*)&Bs[lrow][lcg] = *(const uint4*)(Wg + (size_t)(n0+lrow)*Kd + k0 + lcg);
    __syncthreads();
    bf16x8 af = *(const bf16x8*)&As[w*16 + frow][quad*8];
    #pragma unroll
    for (int t=0;t<4;t++){
      bf16x8 bfr = *(const bf16x8*)&Bs[t*16 + frow][quad*8];
      acc[t] = __builtin_amdgcn_mfma_f32_16x16x32_bf16(af, bfr, acc[t], 0, 0, 0);
    }
  }

  #pragma unroll
  for (int t=0;t<4;t++){
    int col = n0 + t*16 + frow;
    float bv = bf2f(bias[col]);
    #pragma unroll
    for (int r=0;r<4;r++){
      int row = m0 + w*16 + quad*4 + r;
      Cg[(size_t)row*Nn + col] = f2bf(acc[t][r] + bv);
    }
  }
}

// ---------------------------------------------------------------------------
// K5: per-(b,h) attention, S=512, HD=32. One thread per query row, online
// softmax (base-2), K/V staged bf16 in LDS (64KB). att overwrites q_buf.
// Mask is all-true (batch is exactly regular: 512 nodes per graph).
// ---------------------------------------------------------------------------
__launch_bounds__(512)
__global__ void attn_kernel(u16* __restrict__ q_buf, const u16* __restrict__ k_buf,
                            const u16* __restrict__ v_buf){
  __shared__ u16 Ks[512][32];
  __shared__ u16 Vs[512][32];
  int b = blockIdx.x >> 3;
  int h = blockIdx.x & 7;
  int s = threadIdx.x;
  size_t rowoff = (size_t)b*512*256 + (size_t)h*32;

  { // stage K,V row s (64B each)
    const uint4* kp = (const uint4*)(k_buf + rowoff + (size_t)s*256);
    const uint4* vp = (const uint4*)(v_buf + rowoff + (size_t)s*256);
    uint4* kd = (uint4*)&Ks[s][0];
    uint4* vd = (uint4*)&Vs[s][0];
    #pragma unroll
    for (int i=0;i<4;i++){ kd[i]=kp[i]; vd[i]=vp[i]; }
  }

  float q[32];
  { // load own query, pre-scale by (1/sqrt(32))*log2(e) for base-2 softmax
    const float c = 0.17677669529663687f * 1.4426950408889634f;
    const uint4* qp = (const uint4*)(q_buf + rowoff + (size_t)s*256);
    #pragma unroll
    for (int i=0;i<4;i++){
      uint4 p = qp[i];
      u32 uu[4]={p.x,p.y,p.z,p.w};
      #pragma unroll
      for (int t=0;t<4;t++){
        q[i*8+2*t]   = __uint_as_float(uu[t]<<16) * c;
        q[i*8+2*t+1] = __uint_as_float(uu[t]&0xffff0000u) * c;
      }
    }
  }
  __syncthreads();

  float m = -3.0e38f, lsum = 0.f;
  float acc[32];
  #pragma unroll
  for (int i=0;i<32;i++) acc[i]=0.f;

  for (int j=0;j<512;j++){
    const uint4* kp = (const uint4*)&Ks[j][0];
    float sc = 0.f;
    #pragma unroll
    for (int i=0;i<4;i++){
      uint4 p = kp[i];
      u32 uu[4]={p.x,p.y,p.z,p.w};
      #pragma unroll
      for (int t=0;t<4;t++){
        sc += q[i*8+2*t]   * __uint_as_float(uu[t]<<16);
        sc += q[i*8+2*t+1] * __uint_as_float(uu[t]&0xffff0000u);
      }
    }
    const uint4* vp = (const uint4*)&Vs[j][0];
    if (sc <= m){                       // common path after warm-up
      float p = exp2f(sc - m);
      lsum += p;
      #pragma unroll
      for (int i=0;i<4;i++){
        uint4 pv = vp[i];
        u32 uu[4]={pv.x,pv.y,pv.z,pv.w};
        #pragma unroll
        for (int t=0;t<4;t++){
          acc[i*8+2*t]   += p*__uint_as_float(uu[t]<<16);
          acc[i*8+2*t+1] += p*__uint_as_float(uu[t]&0xffff0000u);
        }
      }
    } else {
      float alpha = exp2f(m - sc);      // exp2(-huge)=0 on first key
      m = sc;
      lsum = lsum*alpha + 1.f;
      #pragma unroll
      for (int i=0;i<4;i++){
        uint4 pv = vp[i];
        u32 uu[4]={pv.x,pv.y,pv.z,pv.w};
        #pragma unroll
        for (int t=0;t<4;t++){
          acc[i*8+2*t]   = acc[i*8+2*t]*alpha   + __uint_as_float(uu[t]<<16);
          acc[i*8+2*t+1] = acc[i*8+2*t+1]*alpha + __uint_as_float(uu[t]&0xffff0000u);
        }
      }
    }
  }

  float inv = 1.f/lsum;
  u32* op = (u32*)(q_buf + rowoff + (size_t)s*256);   // own slice, safe in-place
  #pragma unroll
  for (int k2=0;k2<16;k2++){
    op[k2] = pack2(acc[2*k2]*inv, acc[2*k2+1]*inv);
  }
}

// ---------------------------------------------------------------------------
// K6: out = LN2(fused + LN1(fused + attn_out)) — one wave per row.
// Output dtype follows detected input dtype: fp32 (flag=1) or bf16 (flag=0).
// ---------------------------------------------------------------------------
__launch_bounds__(256)
__global__ void ln_epilogue_kernel(const u16* __restrict__ fused, const u16* __restrict__ attn_out,
                                   const u16* __restrict__ g1v, const u16* __restrict__ b1v,
                                   const u16* __restrict__ g2v, const u16* __restrict__ b2v,
                                   const int* __restrict__ flag, void* __restrict__ out){
  int wid  = threadIdx.x >> 6;
  int lane = threadIdx.x & 63;
  int row = blockIdx.x*4 + wid;
  int c0 = lane*4;
  size_t off = (size_t)row*256 + c0;
  uint2 pf = *(const uint2*)(fused+off);
  uint2 pa = *(const uint2*)(attn_out+off);
  u32 uf[2]={pf.x,pf.y}, ua[2]={pa.x,pa.y};
  float f[4], a[4];
  #pragma unroll
  for (int j=0;j<2;j++){
    f[2*j]   = __uint_as_float(uf[j]<<16);
    f[2*j+1] = __uint_as_float(uf[j]&0xffff0000u);
    a[2*j]   = __uint_as_float(ua[j]<<16);
    a[2*j+1] = __uint_as_float(ua[j]&0xffff0000u);
  }
  float h[4]; float sum=0.f, ss=0.f;
  #pragma unroll
  for (int i=0;i<4;i++){ h[i]=f[i]+a[i]; sum+=h[i]; ss+=h[i]*h[i]; }
  #pragma unroll
  for (int o2=32;o2>0;o2>>=1){ sum += __shfl_xor(sum,o2,64); ss += __shfl_xor(ss,o2,64); }
  float mean = sum*(1.f/256.f);
  float var  = ss*(1.f/256.f) - mean*mean;
  float rstd = rsqrtf(fmaxf(var,0.f) + 1e-5f);
  float t[4]; float sum2=0.f, ss2=0.f;
  #pragma unroll
  for (int i=0;i<4;i++){
    int c = c0+i;
    float ln = (h[i]-mean)*rstd*bf2f(g1v[c]) + bf2f(b1v[c]);
    t[i] = f[i] + ln;
    sum2 += t[i]; ss2 += t[i]*t[i];
  }
  #pragma unroll
  for (int o2=32;o2>0;o2>>=1){ sum2 += __shfl_xor(sum2,o2,64); ss2 += __shfl_xor(ss2,o2,64); }
  float mean2 = sum2*(1.f/256.f);
  float var2  = ss2*(1.f/256.f) - mean2*mean2;
  float rstd2 = rsqrtf(fmaxf(var2,0.f) + 1e-5f);
  float r0 = (t[0]-mean2)*rstd2*bf2f(g2v[c0])   + bf2f(b2v[c0]);
  float r1 = (t[1]-mean2)*rstd2*bf2f(g2v[c0+1]) + bf2f(b2v[c0+1]);
  float r2 = (t[2]-mean2)*rstd2*bf2f(g2v[c0+2]) + bf2f(b2v[c0+2]);
  float r3 = (t[3]-mean2)*rstd2*bf2f(g2v[c0+3]) + bf2f(b2v[c0+3]);
  if (*flag){
    float4 o4; o4.x=r0; o4.y=r1; o4.z=r2; o4.w=r3;
    *(float4*)((float*)out + off) = o4;
  } else {
    uint2 o; o.x = pack2(r0,r1); o.y = pack2(r2,r3);
    *(uint2*)((u16*)out + off) = o;
  }
}

// ---------------------------------------------------------------------------
extern "C" void kernel_launch(void* const* d_in, const int* in_sizes, int n_in,
                              void* d_out, int out_size, void* d_ws, size_t ws_size,
                              hipStream_t stream) {
  const void* f0 = d_in[0];
  const void* f1 = d_in[1];
  const void* f2 = d_in[2];
  const int* batch = (const int*)d_in[3];

  char* ws = (char*)d_ws;
  int*   flag   = (int*)(ws);
  float* gmean  = (float*)(ws + 4096);            // 393,216 B
  float* scalew = (float*)(ws + 458752);          // 1,536 B
  u16*   wbuf   = (u16*)(ws + 524288);            // 627,072 B converted weights
  u16* fused    = (u16*)(ws + (2u<<20));          // 32 MB each below
  u16* qb       = fused + (size_t)N_*D_;          // q, later att (in-place)
  u16* kb       = qb    + (size_t)N_*D_;          // k, later attn_out (reuse)
  u16* vb       = kb    + (size_t)N_*D_;          // total ~130 MB

  // converted-weight element offsets (order = d_in[4..21])
  static const int sizes[18] = {16384,64,16384,64,16384,64,
                                65536,256,65536,256,65536,256,65536,256,
                                256,256,256,256};
  CvtArgs ca;
  int cum = 0;
  for (int i=0;i<18;i++){ ca.src[i] = d_in[4+i]; ca.cum[i] = cum; cum += sizes[i]; }
  ca.cum[18] = cum;   // 313,536
  const u16* Wq_s = wbuf + 0;
  const u16* bq_s = wbuf + 16384;
  const u16* Wk_s = wbuf + 16448;
  const u16* bk_s = wbuf + 32832;
  const u16* Wv_s = wbuf + 32896;
  const u16* bv_s = wbuf + 49280;
  const u16* Wq   = wbuf + 49344;
  const u16* bq   = wbuf + 114880;
  const u16* Wk   = wbuf + 115136;
  const u16* bk   = wbuf + 180672;
  const u16* Wv   = wbuf + 180928;
  const u16* bv   = wbuf + 246464;
  const u16* Wo   = wbuf + 246720;
  const u16* bo   = wbuf + 312256;
  const u16* ln1g = wbuf + 312512;
  const u16* ln1b = wbuf + 312768;
  const u16* ln2g = wbuf + 313024;
  const u16* ln2b = wbuf + 313280;

  detect_kernel<<<1, 64, 0, stream>>>((const u16*)f0, flag);
  convert_kernel<<<256, 256, 0, stream>>>(ca, flag, wbuf);

  mean_pool_kernel<<<B_*L_, 256, 0, stream>>>(f0, f1, f2, flag, gmean);
  scale_attn_kernel<<<B_, 64, 0, stream>>>(gmean, Wq_s, bq_s, Wk_s, bk_s, Wv_s, bv_s, scalew);
  fuse_kernel<<<(N_*32)/256, 256, 0, stream>>>(f0, f1, f2, batch, flag, scalew, fused);

  dim3 ggrid(D_/64, N_/64);
  gemm_nt_kernel<<<ggrid, 256, 0, stream>>>(fused, Wq, bq, qb, N_, D_, D_);
  gemm_nt_kernel<<<ggrid, 256, 0, stream>>>(fused, Wk, bk, kb, N_, D_, D_);
  gemm_nt_kernel<<<ggrid, 256, 0, stream>>>(fused, Wv, bv, vb, N_, D_, D_);

  attn_kernel<<<B_*H_, 512, 0, stream>>>(qb, kb, vb);

  // attn_out reuses kb (k is dead after attention)
  gemm_nt_kernel<<<ggrid, 256, 0, stream>>>(qb, Wo, bo, kb, N_, D_, D_);

  ln_epilogue_kernel<<<N_/4, 256, 0, stream>>>(fused, kb, ln1g, ln1b, ln2g, ln2b,
                                               flag, d_out);
}

// Round 4
// 763.464 us; speedup vs baseline: 1.8185x; 1.8185x over previous
//
#include <hip/hip_runtime.h>
#include <stdint.h>

typedef unsigned short u16;
typedef unsigned int   u32;

#define B_  128
#define S_  512
#define D_  256
#define L_  3
#define H_  8
#define AD_ 64
#define HD_ 32
#define N_  (B_*S_)

typedef __bf16 bf16x8 __attribute__((ext_vector_type(8)));
typedef float  f32x4  __attribute__((ext_vector_type(4)));

__device__ __forceinline__ float bf2f(u16 u){ return __uint_as_float(((u32)u)<<16); }
__device__ __forceinline__ u16 f2bf(float f){
  u32 u = __float_as_uint(f);
  u32 r = u + 0x7fffu + ((u>>16)&1u);
  return (u16)(r>>16);
}
__device__ __forceinline__ u32 pack2(float lo, float hi){
  return (u32)f2bf(lo) | ((u32)f2bf(hi)<<16);
}
// cheap round-half-up bf16 (for P tiles, values in [0,1])
__device__ __forceinline__ u16 f2bf_fast(float f){
  return (u16)((__float_as_uint(f) + 0x8000u) >> 16);
}

// ---------------------------------------------------------------------------
// K0a: dtype detection (round-2 evidence: flag==1, inputs are fp32).
// ---------------------------------------------------------------------------
__launch_bounds__(64)
__global__ void detect_kernel(const u16* __restrict__ f0, int* __restrict__ flag){
  int lane = threadIdx.x;
  int cnt = 0;
  for (int i = lane; i < 4096; i += 64){
    u16 v = f0[i];
    int e = (v >> 7) & 0xff;
    cnt += (e >= 0x90);
  }
  #pragma unroll
  for (int o=32;o>0;o>>=1) cnt += __shfl_xor(cnt, o, 64);
  if (lane==0) *flag = (cnt > 128) ? 1 : 0;   // 1 => fp32
}

// ---------------------------------------------------------------------------
// K0b: canonicalize the 18 small float arrays to bf16 in ws.
// ---------------------------------------------------------------------------
struct CvtArgs {
  const void* src[18];
  int cum[19];
};

__launch_bounds__(256)
__global__ void convert_kernel(CvtArgs a, const int* __restrict__ flag, u16* __restrict__ dst){
  int isf32 = *flag;
  int total = a.cum[18];
  for (int g = blockIdx.x*blockDim.x + threadIdx.x; g < total; g += gridDim.x*blockDim.x){
    int arr = 0;
    while (g >= a.cum[arr+1]) arr++;
    int idx = g - a.cum[arr];
    float v = isf32 ? ((const float*)a.src[arr])[idx]
                    : bf2f(((const u16*)a.src[arr])[idx]);
    dst[g] = f2bf(v);
  }
}

// ---------------------------------------------------------------------------
// K1: per-(graph, scale) mean pooling over 512 rows -> G_mean [B,L,D] fp32
// ---------------------------------------------------------------------------
__launch_bounds__(256)
__global__ void mean_pool_kernel(const void* __restrict__ f0, const void* __restrict__ f1,
                                 const void* __restrict__ f2, const int* __restrict__ flag,
                                 float* __restrict__ gmean){
  __shared__ float part[8][256];
  int bx = blockIdx.x;
  int l = bx % 3, b = bx / 3;
  const void* f = (l==0)?f0:((l==1)?f1:f2);
  int tid = threadIdx.x;
  int cg = (tid & 31) << 3;
  int sg = tid >> 5;
  int isf32 = *flag;
  float acc[8];
  #pragma unroll
  for (int i=0;i<8;i++) acc[i]=0.f;
  if (isf32){
    const float* base = (const float*)f + (size_t)b*S_*D_;
    for (int s = sg; s < S_; s += 8){
      float4 p0 = *(const float4*)(base + (size_t)s*D_ + cg);
      float4 p1 = *(const float4*)(base + (size_t)s*D_ + cg + 4);
      acc[0]+=p0.x; acc[1]+=p0.y; acc[2]+=p0.z; acc[3]+=p0.w;
      acc[4]+=p1.x; acc[5]+=p1.y; acc[6]+=p1.z; acc[7]+=p1.w;
    }
  } else {
    const u16* base = (const u16*)f + (size_t)b*S_*D_;
    for (int s = sg; s < S_; s += 8){
      uint4 p = *(const uint4*)(base + (size_t)s*D_ + cg);
      u32 uu[4]={p.x,p.y,p.z,p.w};
      #pragma unroll
      for (int j=0;j<4;j++){
        acc[2*j]   += __uint_as_float(uu[j]<<16);
        acc[2*j+1] += __uint_as_float(uu[j]&0xffff0000u);
      }
    }
  }
  #pragma unroll
  for (int j=0;j<8;j++) part[sg][cg+j] = acc[j];
  __syncthreads();
  float s2 = 0.f;
  #pragma unroll
  for (int g=0; g<8; g++) s2 += part[g][tid];
  gmean[(size_t)(b*3+l)*256 + tid] = s2 * (1.0f/512.0f);
}

// ---------------------------------------------------------------------------
// K2: tiny per-graph scale attention -> scale_w [B,L] fp32.  1 wave / graph.
// ---------------------------------------------------------------------------
__launch_bounds__(64)
__global__ void scale_attn_kernel(const float* __restrict__ gmean,
                                  const u16* __restrict__ Wq_s, const u16* __restrict__ bq_s,
                                  const u16* __restrict__ Wk_s, const u16* __restrict__ bk_s,
                                  const u16* __restrict__ Wv_s, const u16* __restrict__ bv_s,
                                  float* __restrict__ scale_w){
  __shared__ float G[3][256];
  __shared__ float qs[3][64], ks[3][64], vs[3][64];
  __shared__ float A[3][3];
  __shared__ float sw[3];
  int a = threadIdx.x;
  int b = blockIdx.x;
  for (int i = a; i < 3*256; i += 64) ((float*)G)[i] = gmean[(size_t)b*768 + i];
  if (a < 3) sw[a] = 0.f;
  __syncthreads();
  for (int l=0;l<3;l++){
    float accq = bf2f(bq_s[a]), acck = bf2f(bk_s[a]), accv = bf2f(bv_s[a]);
    for (int d=0; d<256; d++){
      float g = G[l][d];
      accq += g * bf2f(Wq_s[a*256+d]);
      acck += g * bf2f(Wk_s[a*256+d]);
      accv += g * bf2f(Wv_s[a*256+d]);
    }
    qs[l][a]=accq; ks[l][a]=acck; vs[l][a]=accv;
  }
  __syncthreads();
  if (a < 9){
    int l=a/3, m=a%3;
    float s=0.f;
    for (int j=0;j<64;j++) s += qs[l][j]*ks[m][j];
    A[l][m] = s * 0.125f;
  }
  __syncthreads();
  if (a < 3){
    float mx = fmaxf(A[a][0], fmaxf(A[a][1],A[a][2]));
    float e0=expf(A[a][0]-mx), e1=expf(A[a][1]-mx), e2=expf(A[a][2]-mx);
    float inv = 1.f/(e0+e1+e2);
    A[a][0]=e0*inv; A[a][1]=e1*inv; A[a][2]=e2*inv;
  }
  __syncthreads();
  float g0=0.f,g1=0.f,g2=0.f;
  for (int m=0;m<3;m++){
    float v = vs[m][a];
    g0 += A[0][m]*v; g1 += A[1][m]*v; g2 += A[2][m]*v;
  }
  float mx = fmaxf(g0,fmaxf(g1,g2));
  float e0=expf(g0-mx), e1=expf(g1-mx), e2=expf(g2-mx);
  float inv = 1.f/(e0+e1+e2);
  atomicAdd(&sw[0], e0*inv);
  atomicAdd(&sw[1], e1*inv);
  atomicAdd(&sw[2], e2*inv);
  __syncthreads();
  if (a < 3) scale_w[b*3+a] = sw[a] * (1.0f/64.0f);
}

// ---------------------------------------------------------------------------
// K3: fused[n,:] = sum_l w[batch[n],l] * feat_l[n,:]   (bf16 out)
// ---------------------------------------------------------------------------
__launch_bounds__(256)
__global__ void fuse_kernel(const void* __restrict__ f0, const void* __restrict__ f1,
                            const void* __restrict__ f2, const int* __restrict__ batch,
                            const int* __restrict__ flag,
                            const float* __restrict__ scale_w, u16* __restrict__ fused){
  int idx = blockIdx.x*256 + threadIdx.x;
  int n  = idx >> 5;
  int c8 = (idx & 31) << 3;
  int b = batch[n];
  int isf32 = *flag;
  float w0 = scale_w[b*3+0], w1 = scale_w[b*3+1], w2 = scale_w[b*3+2];
  size_t off = (size_t)n*256 + c8;
  float e[8];
  if (isf32){
    const float* p0 = (const float*)f0 + off;
    const float* p1 = (const float*)f1 + off;
    const float* p2 = (const float*)f2 + off;
    float4 a0 = *(const float4*)(p0),   a1 = *(const float4*)(p0+4);
    float4 b0 = *(const float4*)(p1),   b1 = *(const float4*)(p1+4);
    float4 c0 = *(const float4*)(p2),   c1 = *(const float4*)(p2+4);
    e[0]=w0*a0.x+w1*b0.x+w2*c0.x; e[1]=w0*a0.y+w1*b0.y+w2*c0.y;
    e[2]=w0*a0.z+w1*b0.z+w2*c0.z; e[3]=w0*a0.w+w1*b0.w+w2*c0.w;
    e[4]=w0*a1.x+w1*b1.x+w2*c1.x; e[5]=w0*a1.y+w1*b1.y+w2*c1.y;
    e[6]=w0*a1.z+w1*b1.z+w2*c1.z; e[7]=w0*a1.w+w1*b1.w+w2*c1.w;
  } else {
    uint4 p0 = *(const uint4*)((const u16*)f0+off);
    uint4 p1 = *(const uint4*)((const u16*)f1+off);
    uint4 p2 = *(const uint4*)((const u16*)f2+off);
    u32 a0[4]={p0.x,p0.y,p0.z,p0.w}, a1[4]={p1.x,p1.y,p1.z,p1.w}, a2[4]={p2.x,p2.y,p2.z,p2.w};
    #pragma unroll
    for (int j=0;j<4;j++){
      e[2*j]   = w0*__uint_as_float(a0[j]<<16) + w1*__uint_as_float(a1[j]<<16)
               + w2*__uint_as_float(a2[j]<<16);
      e[2*j+1] = w0*__uint_as_float(a0[j]&0xffff0000u) + w1*__uint_as_float(a1[j]&0xffff0000u)
               + w2*__uint_as_float(a2[j]&0xffff0000u);
    }
  }
  uint4 o;
  o.x = pack2(e[0],e[1]); o.y = pack2(e[2],e[3]);
  o.z = pack2(e[4],e[5]); o.w = pack2(e[6],e[7]);
  *(uint4*)(fused+off) = o;
}

// ---------------------------------------------------------------------------
// K4: NT GEMM  C[M,N] = X[M,K] @ W[N,K]^T + bias, bf16 in/out, fp32 acc.
// ---------------------------------------------------------------------------
__launch_bounds__(256)
__global__ void gemm_nt_kernel(const u16* __restrict__ Xg, const u16* __restrict__ Wg,
                               const u16* __restrict__ bias, u16* __restrict__ Cg,
                               int M, int Nn, int Kd){
  __shared__ __align__(16) __bf16 As[64][40];
  __shared__ __align__(16) __bf16 Bs[64][40];
  int tid = threadIdx.x;
  int w = tid >> 6, l = tid & 63;
  int m0 = blockIdx.y*64, n0 = blockIdx.x*64;
  int lrow = tid >> 2;
  int lcg  = (tid & 3) << 3;
  int frow = l & 15, quad = l >> 4;

  f32x4 acc[4];
  #pragma unroll
  for (int t=0;t<4;t++){
    #pragma unroll
    for (int i=0;i<4;i++) acc[t][i] = 0.f;
  }

  for (int k0 = 0; k0 < Kd; k0 += 32){
    __syncthreads();
    *(uint4*)&As[lrow][lcg] = *(const uint4*)(Xg + (size_t)(m0+lrow)*Kd + k0 + lcg);
    *(uint4*)&Bs[lrow][lcg] = *(const uint4*)(Wg + (size_t)(n0+lrow)*Kd + k0 + lcg);
    __syncthreads();
    bf16x8 af = *(const bf16x8*)&As[w*16 + frow][quad*8];
    #pragma unroll
    for (int t=0;t<4;t++){
      bf16x8 bfr = *(const bf16x8*)&Bs[t*16 + frow][quad*8];
      acc[t] = __builtin_amdgcn_mfma_f32_16x16x32_bf16(af, bfr, acc[t], 0, 0, 0);
    }
  }

  #pragma unroll
  for (int t=0;t<4;t++){
    int col = n0 + t*16 + frow;
    float bv = bf2f(bias[col]);
    #pragma unroll
    for (int r=0;r<4;r++){
      int row = m0 + w*16 + quad*4 + r;
      Cg[(size_t)row*Nn + col] = f2bf(acc[t][r] + bv);
    }
  }
}

// ---------------------------------------------------------------------------
// K5: MFMA flash attention. One block = one (b,h); 4 waves x 8 q-frags of 16.
// K [512][32] and V^T [32][512] staged in LDS; k-loop has NO barriers.
// Score tile:  S[16q,16k] = mfma_16x16x32(Qfrag, Kfrag)  (HD=32 = one MFMA)
// C-layout: col(lane&15)=key, row(quad*4+reg)=query.  Online softmax state
// per lane covers its 4 rows; row reduce = shfl_xor over lane&15 group.
// P C-layout -> A-layout via per-wave LDS round trip (m120-verified pattern).
// PV: D[16q,32d] = 2x mfma(Pfrag, Vt-frag).  Output in-place into q_buf.
// ---------------------------------------------------------------------------
__launch_bounds__(256)
__global__ void attn_mfma_kernel(u16* __restrict__ q_buf, const u16* __restrict__ k_buf,
                                 const u16* __restrict__ v_buf){
  __shared__ __align__(16) __bf16 Ks[512][40];   // pad->80B rows: 16B-aligned
  __shared__ __align__(16) __bf16 Vt[32][520];   // pad->1040B rows
  __shared__ __align__(16) __bf16 Pb[4][16][40]; // per-wave P buffer
  int tid = threadIdx.x;
  int b = blockIdx.x >> 3, h = blockIdx.x & 7;
  size_t base = (size_t)b*512*256 + (size_t)h*32;   // elem offset of row 0, this head

  // ---- stage K: 512 rows x 64B, coalesced 16B chunks ----
  #pragma unroll
  for (int i=0;i<8;i++){
    int c = tid + i*256;              // 0..2047
    int row = c>>2, cg = (c&3)<<3;
    uint4 p = *(const uint4*)(k_buf + base + (size_t)row*256 + cg);
    *(uint4*)&Ks[row][cg] = p;
  }
  // ---- stage V transposed: thread t owns rows 2t, 2t+1 ----
  {
    int r0 = tid*2;
    const uint4* p0 = (const uint4*)(v_buf + base + (size_t)r0*256);
    const uint4* p1 = (const uint4*)(v_buf + base + (size_t)(r0+1)*256);
    u32 w0[8], w1[8];
    #pragma unroll
    for (int i=0;i<4;i++){
      uint4 a = p0[i]; w0[2*i]=a.x; w0[2*i+1]=a.z;   // careful: keep order
      uint4 bq4 = p1[i]; w1[2*i]=bq4.x; w1[2*i+1]=bq4.z;
      // need y,w too — handle below with full array
    }
    // redo cleanly: load into u32[8] per row
    uint4 a0=p0[0], a1=p0[1], a2=p0[2], a3=p0[3];
    uint4 b0=p1[0], b1=p1[1], b2=p1[2], b3=p1[3];
    u32 ra[8] = {a0.x,a0.y,a0.z,a0.w,a1.x,a1.y,a1.z,a1.w};
    u32 rb[8] = {b0.x,b0.y,b0.z,b0.w,b1.x,b1.y,b1.z,b1.w};
    u32 rc[8] = {a2.x,a2.y,a2.z,a2.w,a3.x,a3.y,a3.z,a3.w};
    u32 rd[8] = {b2.x,b2.y,b2.z,b2.w,b3.x,b3.y,b3.z,b3.w};
    #pragma unroll
    for (int j=0;j<8;j++){            // cols 2j, 2j+1 of first 16 d's
      u32 lo = (ra[j]&0xffffu) | (rb[j]<<16);           // d=2j
      u32 hi = (ra[j]>>16)     | (rb[j]&0xffff0000u);   // d=2j+1
      *(u32*)&Vt[2*j][r0]   = lo;
      *(u32*)&Vt[2*j+1][r0] = hi;
    }
    #pragma unroll
    for (int j=0;j<8;j++){            // d = 16+2j, 16+2j+1
      u32 lo = (rc[j]&0xffffu) | (rd[j]<<16);
      u32 hi = (rc[j]>>16)     | (rd[j]&0xffff0000u);
      *(u32*)&Vt[16+2*j][r0]   = lo;
      *(u32*)&Vt[16+2*j+1][r0] = hi;
    }
  }
  __syncthreads();

  int wv = tid>>6, lane = tid&63;
  int fr = lane&15, quad = lane>>4;
  const float cs = 0.17677669529663687f * 1.4426950408889634f; // 1/sqrt(32)*log2(e)
  const f32x4 zf = {0.f,0.f,0.f,0.f};

  for (int it=0; it<8; it++){
    int qrow0 = it*64 + wv*16;
    bf16x8 qf = *(const bf16x8*)(q_buf + base + (size_t)(qrow0+fr)*256 + quad*8);

    float m0[4], l0[4];
    f32x4 O0 = zf, O1 = zf;
    #pragma unroll
    for (int r=0;r<4;r++){ m0[r] = -3.0e38f; l0[r] = 0.f; }

    for (int kt=0; kt<512; kt+=32){
      bf16x8 kf0 = *(const bf16x8*)&Ks[kt+fr][quad*8];
      bf16x8 kf1 = *(const bf16x8*)&Ks[kt+16+fr][quad*8];
      f32x4 s0 = __builtin_amdgcn_mfma_f32_16x16x32_bf16(qf, kf0, zf, 0,0,0);
      f32x4 s1 = __builtin_amdgcn_mfma_f32_16x16x32_bf16(qf, kf1, zf, 0,0,0);

      float p0v[4], p1v[4];
      #pragma unroll
      for (int r=0;r<4;r++){
        float a = s0[r]*cs, bb = s1[r]*cs;
        float t = fmaxf(a,bb);
        t = fmaxf(t, __shfl_xor(t,1));
        t = fmaxf(t, __shfl_xor(t,2));
        t = fmaxf(t, __shfl_xor(t,4));
        t = fmaxf(t, __shfl_xor(t,8));
        float nm = fmaxf(m0[r], t);
        float al = exp2f(m0[r]-nm);
        m0[r] = nm;
        float p0 = exp2f(a-nm), p1 = exp2f(bb-nm);
        p0v[r]=p0; p1v[r]=p1;
        float rs = p0+p1;
        rs += __shfl_xor(rs,1);
        rs += __shfl_xor(rs,2);
        rs += __shfl_xor(rs,4);
        rs += __shfl_xor(rs,8);
        l0[r] = l0[r]*al + rs;
        O0[r]*=al; O1[r]*=al;
      }
      #pragma unroll
      for (int r=0;r<4;r++){
        *(u16*)&Pb[wv][quad*4+r][fr]    = f2bf_fast(p0v[r]);
        *(u16*)&Pb[wv][quad*4+r][16+fr] = f2bf_fast(p1v[r]);
      }
      asm volatile("s_waitcnt lgkmcnt(0)" ::: "memory");
      bf16x8 pa  = *(const bf16x8*)&Pb[wv][fr][quad*8];
      bf16x8 vb0 = *(const bf16x8*)&Vt[fr][kt+quad*8];
      bf16x8 vb1 = *(const bf16x8*)&Vt[16+fr][kt+quad*8];
      O0 = __builtin_amdgcn_mfma_f32_16x16x32_bf16(pa, vb0, O0, 0,0,0);
      O1 = __builtin_amdgcn_mfma_f32_16x16x32_bf16(pa, vb1, O1, 0,0,0);
    }

    // normalize + in-place write (lane pairs pack 2 bf16 -> u32)
    #pragma unroll
    for (int r=0;r<4;r++){
      float inv = 1.f/l0[r];
      float v0 = O0[r]*inv, v1 = O1[r]*inv;
      float v0p = __shfl_xor(v0,1), v1p = __shfl_xor(v1,1);
      if (!(lane&1)){
        int qr = qrow0 + quad*4 + r;
        u32* dst = (u32*)(q_buf + base + (size_t)qr*256);
        dst[fr>>1]       = pack2(v0, v0p);
        dst[8+(fr>>1)]   = pack2(v1, v1p);
      }
    }
  }
}

// ---------------------------------------------------------------------------
// K6: out = LN2(fused + LN1(fused + attn_out)) — one wave per row.
// ---------------------------------------------------------------------------
__launch_bounds__(256)
__global__ void ln_epilogue_kernel(const u16* __restrict__ fused, const u16* __restrict__ attn_out,
                                   const u16* __restrict__ g1v, const u16* __restrict__ b1v,
                                   const u16* __restrict__ g2v, const u16* __restrict__ b2v,
                                   const int* __restrict__ flag, void* __restrict__ out){
  int wid  = threadIdx.x >> 6;
  int lane = threadIdx.x & 63;
  int row = blockIdx.x*4 + wid;
  int c0 = lane*4;
  size_t off = (size_t)row*256 + c0;
  uint2 pf = *(const uint2*)(fused+off);
  uint2 pa = *(const uint2*)(attn_out+off);
  u32 uf[2]={pf.x,pf.y}, ua[2]={pa.x,pa.y};
  float f[4], a[4];
  #pragma unroll
  for (int j=0;j<2;j++){
    f[2*j]   = __uint_as_float(uf[j]<<16);
    f[2*j+1] = __uint_as_float(uf[j]&0xffff0000u);
    a[2*j]   = __uint_as_float(ua[j]<<16);
    a[2*j+1] = __uint_as_float(ua[j]&0xffff0000u);
  }
  float h[4]; float sum=0.f, ss=0.f;
  #pragma unroll
  for (int i=0;i<4;i++){ h[i]=f[i]+a[i]; sum+=h[i]; ss+=h[i]*h[i]; }
  #pragma unroll
  for (int o2=32;o2>0;o2>>=1){ sum += __shfl_xor(sum,o2,64); ss += __shfl_xor(ss,o2,64); }
  float mean = sum*(1.f/256.f);
  float var  = ss*(1.f/256.f) - mean*mean;
  float rstd = rsqrtf(fmaxf(var,0.f) + 1e-5f);
  float t[4]; float sum2=0.f, ss2=0.f;
  #pragma unroll
  for (int i=0;i<4;i++){
    int c = c0+i;
    float ln = (h[i]-mean)*rstd*bf2f(g1v[c]) + bf2f(b1v[c]);
    t[i] = f[i] + ln;
    sum2 += t[i]; ss2 += t[i]*t[i];
  }
  #pragma unroll
  for (int o2=32;o2>0;o2>>=1){ sum2 += __shfl_xor(sum2,o2,64); ss2 += __shfl_xor(ss2,o2,64); }
  float mean2 = sum2*(1.f/256.f);
  float var2  = ss2*(1.f/256.f) - mean2*mean2;
  float rstd2 = rsqrtf(fmaxf(var2,0.f) + 1e-5f);
  float r0 = (t[0]-mean2)*rstd2*bf2f(g2v[c0])   + bf2f(b2v[c0]);
  float r1 = (t[1]-mean2)*rstd2*bf2f(g2v[c0+1]) + bf2f(b2v[c0+1]);
  float r2 = (t[2]-mean2)*rstd2*bf2f(g2v[c0+2]) + bf2f(b2v[c0+2]);
  float r3 = (t[3]-mean2)*rstd2*bf2f(g2v[c0+3]) + bf2f(b2v[c0+3]);
  if (*flag){
    float4 o4; o4.x=r0; o4.y=r1; o4.z=r2; o4.w=r3;
    *(float4*)((float*)out + off) = o4;
  } else {
    uint2 o; o.x = pack2(r0,r1); o.y = pack2(r2,r3);
    *(uint2*)((u16*)out + off) = o;
  }
}

// ---------------------------------------------------------------------------
extern "C" void kernel_launch(void* const* d_in, const int* in_sizes, int n_in,
                              void* d_out, int out_size, void* d_ws, size_t ws_size,
                              hipStream_t stream) {
  const void* f0 = d_in[0];
  const void* f1 = d_in[1];
  const void* f2 = d_in[2];
  const int* batch = (const int*)d_in[3];

  char* ws = (char*)d_ws;
  int*   flag   = (int*)(ws);
  float* gmean  = (float*)(ws + 4096);
  float* scalew = (float*)(ws + 458752);
  u16*   wbuf   = (u16*)(ws + 524288);
  u16* fused    = (u16*)(ws + (2u<<20));
  u16* qb       = fused + (size_t)N_*D_;
  u16* kb       = qb    + (size_t)N_*D_;
  u16* vb       = kb    + (size_t)N_*D_;

  static const int sizes[18] = {16384,64,16384,64,16384,64,
                                65536,256,65536,256,65536,256,65536,256,
                                256,256,256,256};
  CvtArgs ca;
  int cum = 0;
  for (int i=0;i<18;i++){ ca.src[i] = d_in[4+i]; ca.cum[i] = cum; cum += sizes[i]; }
  ca.cum[18] = cum;
  const u16* Wq_s = wbuf + 0;
  const u16* bq_s = wbuf + 16384;
  const u16* Wk_s = wbuf + 16448;
  const u16* bk_s = wbuf + 32832;
  const u16* Wv_s = wbuf + 32896;
  const u16* bv_s = wbuf + 49280;
  const u16* Wq   = wbuf + 49344;
  const u16* bq   = wbuf + 114880;
  const u16* Wk   = wbuf + 115136;
  const u16* bk   = wbuf + 180672;
  const u16* Wv   = wbuf + 180928;
  const u16* bv   = wbuf + 246464;
  const u16* Wo   = wbuf + 246720;
  const u16* bo   = wbuf + 312256;
  const u16* ln1g = wbuf + 312512;
  const u16* ln1b = wbuf + 312768;
  const u16* ln2g = wbuf + 313024;
  const u16* ln2b = wbuf + 313280;

  detect_kernel<<<1, 64, 0, stream>>>((const u16*)f0, flag);
  convert_kernel<<<256, 256, 0, stream>>>(ca, flag, wbuf);

  mean_pool_kernel<<<B_*L_, 256, 0, stream>>>(f0, f1, f2, flag, gmean);
  scale_attn_kernel<<<B_, 64, 0, stream>>>(gmean, Wq_s, bq_s, Wk_s, bk_s, Wv_s, bv_s, scalew);
  fuse_kernel<<<(N_*32)/256, 256, 0, stream>>>(f0, f1, f2, batch, flag, scalew, fused);

  dim3 ggrid(D_/64, N_/64);
  gemm_nt_kernel<<<ggrid, 256, 0, stream>>>(fused, Wq, bq, qb, N_, D_, D_);
  gemm_nt_kernel<<<ggrid, 256, 0, stream>>>(fused, Wk, bk, kb, N_, D_, D_);
  gemm_nt_kernel<<<ggrid, 256, 0, stream>>>(fused, Wv, bv, vb, N_, D_, D_);

  attn_mfma_kernel<<<B_*H_, 256, 0, stream>>>(qb, kb, vb);

  gemm_nt_kernel<<<ggrid, 256, 0, stream>>>(qb, Wo, bo, kb, N_, D_, D_);

  ln_epilogue_kernel<<<N_/4, 256, 0, stream>>>(fused, kb, ln1g, ln1b, ln2g, ln2b,
                                               flag, d_out);
}